// Round 1
// baseline (311.629 us; speedup 1.0000x reference)
//
#include <hip/hip_runtime.h>

// Problem constants
#define N_ROWS 131072   // 32*4096
#define D 64
#define K_CODES 1024
// argmin GEMM tile
#define BR 64           // rows per block
#define BC 128          // codes per LDS chunk
#define TR 4            // rows per thread
#define TC 8            // codes per thread
// threads = (BR/TR)*(BC/TC) = 16*16 = 256

// ---------------------------------------------------------------------------
// K0: per-code squared norm + zero the loss accumulator (d_out[0])
// ---------------------------------------------------------------------------
__global__ void csqr_kernel(const float* __restrict__ CB,
                            float* __restrict__ csqr,
                            float* __restrict__ loss) {
    int k = blockIdx.x * 256 + threadIdx.x;   // grid 4*256 = 1024
    if (k == 0) *loss = 0.0f;
    if (k >= K_CODES) return;
    const float4* p = (const float4*)(CB + (size_t)k * D);
    float s = 0.0f;
#pragma unroll
    for (int i = 0; i < D / 4; ++i) {
        float4 v = p[i];
        s += v.x * v.x + v.y * v.y + v.z * v.z + v.w * v.w;
    }
    csqr[k] = s;
}

// ---------------------------------------------------------------------------
// K1: register-tiled GEMM + fused argmin.
// Block computes 64 rows x all 1024 codes (in 8 chunks of 128 staged in LDS).
// Thread (tr,tc) owns 4 rows x 8 codes per chunk. score = csqr[c] - 2*dot.
// ---------------------------------------------------------------------------
__global__ __launch_bounds__(256, 2)
void argmin_kernel(const float* __restrict__ X, const float* __restrict__ CB,
                   const float* __restrict__ csqr,
                   int* __restrict__ idx_out, float* __restrict__ idxf_out) {
    // [d][row] and [d][code], padded so row-stride is a multiple of 16B and
    // not a multiple of 128B (68*4=272B, 132*4=528B) -> conflict-light.
    __shared__ __align__(16) float Xs[64][68];
    __shared__ __align__(16) float Cs[64][132];

    const int t  = threadIdx.x;
    const int tr = t & 15;    // row group  (rows tr*4 .. tr*4+3)
    const int tc = t >> 4;    // code group (codes tc*8 .. tc*8+7)
    const int row0 = blockIdx.x * BR;

    // Stage X tile: Xs[d][r] = X[(row0+r)*64 + d]; coalesced float4 reads.
#pragma unroll
    for (int i = 0; i < 4; ++i) {
        int q  = i * 256 + t;           // 0..1023 (float4 id)
        int r  = q >> 4;                // 0..63
        int d4 = (q & 15) << 2;         // 0,4,...,60
        float4 v = ((const float4*)(X + (size_t)(row0 + r) * D))[q & 15];
        Xs[d4 + 0][r] = v.x;
        Xs[d4 + 1][r] = v.y;
        Xs[d4 + 2][r] = v.z;
        Xs[d4 + 3][r] = v.w;
    }

    float bestd[TR];
    int   besti[TR];
#pragma unroll
    for (int r = 0; r < TR; ++r) { bestd[r] = 3.0e38f; besti[r] = 0; }

    for (int chunk = 0; chunk < K_CODES / BC; ++chunk) {
        __syncthreads();   // protect Cs (and Xs on first iter) from readers
        // Stage codebook chunk: Cs[d][c] = CB[(chunk*128+c)*64 + d]
#pragma unroll
        for (int i = 0; i < 8; ++i) {
            int q  = i * 256 + t;       // 0..2047 (float4 id)
            int c  = q >> 4;            // 0..127
            int d4 = (q & 15) << 2;
            float4 v =
                ((const float4*)(CB + (size_t)(chunk * BC + c) * D))[q & 15];
            Cs[d4 + 0][c] = v.x;
            Cs[d4 + 1][c] = v.y;
            Cs[d4 + 2][c] = v.z;
            Cs[d4 + 3][c] = v.w;
        }
        __syncthreads();

        float acc[TR][TC];
#pragma unroll
        for (int r = 0; r < TR; ++r)
#pragma unroll
            for (int j = 0; j < TC; ++j) acc[r][j] = 0.0f;

#pragma unroll 4
        for (int d = 0; d < D; ++d) {
            float4 av = *(const float4*)&Xs[d][tr * 4];
            float4 b0 = *(const float4*)&Cs[d][tc * 8];
            float4 b1 = *(const float4*)&Cs[d][tc * 8 + 4];
            float a[TR] = {av.x, av.y, av.z, av.w};
            float b[TC] = {b0.x, b0.y, b0.z, b0.w, b1.x, b1.y, b1.z, b1.w};
#pragma unroll
            for (int r = 0; r < TR; ++r)
#pragma unroll
                for (int j = 0; j < TC; ++j)
                    acc[r][j] = fmaf(a[r], b[j], acc[r][j]);
        }

        // Epilogue: score = csqr - 2*dot. Codes ascend with (chunk, j), so
        // strict < keeps the first minimum (np.argmin semantics).
#pragma unroll
        for (int j = 0; j < TC; ++j) {
            int c = chunk * BC + tc * 8 + j;
            float cs = csqr[c];
#pragma unroll
            for (int r = 0; r < TR; ++r) {
                float s = fmaf(-2.0f, acc[r][j], cs);
                if (s < bestd[r]) { bestd[r] = s; besti[r] = c; }
            }
        }
    }

    // Cross-thread reduce over the 16 code-groups per row. Alias onto Cs.
    __syncthreads();
    float (*redD)[17] = (float (*)[17])&Cs[0][0];          // 64*17 floats
    int   (*redI)[17] = (int (*)[17])(((float*)&Cs[0][0]) + 64 * 17);
#pragma unroll
    for (int r = 0; r < TR; ++r) {
        redD[tr * 4 + r][tc] = bestd[r];
        redI[tr * 4 + r][tc] = besti[r];
    }
    __syncthreads();
    if (t < BR) {
        float bd = redD[t][0];
        int   bi = redI[t][0];
#pragma unroll
        for (int i = 1; i < 16; ++i) {
            float dd = redD[t][i];
            int   ii = redI[t][i];
            if (dd < bd || (dd == bd && ii < bi)) { bd = dd; bi = ii; }
        }
        int grow = row0 + t;
        idx_out[grow]  = bi;
        idxf_out[grow] = (float)bi;
    }
}

// ---------------------------------------------------------------------------
// K2: gather z_q = codebook[idx], accumulate loss = 1.25*mean((x-q)^2)
// ---------------------------------------------------------------------------
__global__ __launch_bounds__(256)
void gather_kernel(const float* __restrict__ X, const float* __restrict__ CB,
                   const int* __restrict__ idx,
                   float* __restrict__ zq, float* __restrict__ loss) {
    const int tid    = blockIdx.x * 256 + threadIdx.x;
    const int nquads = N_ROWS * (D / 4);       // float4 units
    const int stride = gridDim.x * 256;
    float acc = 0.0f;
    for (int q = tid; q < nquads; q += stride) {
        int row = q >> 4;          // 16 float4 per row
        int d4  = q & 15;
        int k   = idx[row];
        float4 x = ((const float4*)X)[q];
        float4 c = ((const float4*)(CB + (size_t)k * D))[d4];
        ((float4*)zq)[q] = c;      // z_q forward value == quantize
        float dx = x.x - c.x, dy = x.y - c.y, dz = x.z - c.z, dw = x.w - c.w;
        acc += dx * dx + dy * dy + dz * dz + dw * dw;
    }
    __shared__ float red[256];
    red[threadIdx.x] = acc;
    __syncthreads();
    for (int s = 128; s > 0; s >>= 1) {
        if (threadIdx.x < s) red[threadIdx.x] += red[threadIdx.x + s];
        __syncthreads();
    }
    if (threadIdx.x == 0)
        atomicAdd(loss, red[0] * (1.25f / (float)(N_ROWS * D)));
}

// ---------------------------------------------------------------------------
extern "C" void kernel_launch(void* const* d_in, const int* in_sizes, int n_in,
                              void* d_out, int out_size, void* d_ws,
                              size_t ws_size, hipStream_t stream) {
    const float* X  = (const float*)d_in[0];   // inputs  [131072,64]
    const float* CB = (const float*)d_in[1];   // codebook [1024,64]

    float* out  = (float*)d_out;
    float* loss = out;                                   // [0]
    float* zq   = out + 1;                               // [1 .. 8388608]
    float* idxf = out + 1 + (size_t)N_ROWS * D;          // indices as float

    float* csqr = (float*)d_ws;                          // 1024 floats
    int*   idx  = (int*)((char*)d_ws + 4096);            // 131072 ints

    hipLaunchKernelGGL(csqr_kernel, dim3(4), dim3(256), 0, stream,
                       CB, csqr, loss);
    hipLaunchKernelGGL(argmin_kernel, dim3(N_ROWS / BR), dim3(256), 0, stream,
                       X, CB, csqr, idx, idxf);
    hipLaunchKernelGGL(gather_kernel, dim3(512), dim3(256), 0, stream,
                       X, CB, idx, zq, loss);
}

// Round 2
// 175.426 us; speedup vs baseline: 1.7764x; 1.7764x over previous
//
#include <hip/hip_runtime.h>

// Problem constants
#define N_ROWS 131072   // 32*4096
#define D 64
#define K_CODES 1024

typedef _Float16 f16x8 __attribute__((ext_vector_type(8)));
typedef _Float16 f16x4 __attribute__((ext_vector_type(4)));
typedef float    f32x4 __attribute__((ext_vector_type(4)));

// ---------------------------------------------------------------------------
// K0: per-code squared norm (fp32) + zero the loss accumulator (d_out[0])
// ---------------------------------------------------------------------------
__global__ void csqr_kernel(const float* __restrict__ CB,
                            float* __restrict__ csqr,
                            float* __restrict__ loss) {
    int k = blockIdx.x * 256 + threadIdx.x;   // grid 4*256 = 1024
    if (k == 0) *loss = 0.0f;
    if (k >= K_CODES) return;
    const float4* p = (const float4*)(CB + (size_t)k * D);
    float s = 0.0f;
#pragma unroll
    for (int i = 0; i < D / 4; ++i) {
        float4 v = p[i];
        s += v.x * v.x + v.y * v.y + v.z * v.z + v.w * v.w;
    }
    csqr[k] = s;
}

// ---------------------------------------------------------------------------
// K1: split-f16 MFMA GEMM + fused argmin.
// Block = 4 waves; wave w owns 64 rows (4 M-tiles of 16). A = X rows as
// f16 hi+lo fragments held in registers. B = codebook chunk (64 codes) in
// LDS as f16 hi|lo. dot(x,c) = xh*ch + xl*ch + xh*cl + xl*cl via 8 MFMAs
// (16x16x32_f16) per (Mtile, coltile) -> fp32-level precision (~2^-22 rel).
// score = csqr[c] - 2*dot (||x||^2 dropped; constant per row).
// ---------------------------------------------------------------------------
__global__ __launch_bounds__(256, 2)
void argmin_kernel(const float* __restrict__ X, const float* __restrict__ CB,
                   const float* __restrict__ csqr,
                   int* __restrict__ idx_out, float* __restrict__ idxf_out) {
    // [code][k]: k 0..63 = hi, 64..127 = lo, pad to 136 (272 B row stride:
    // 16B-aligned, bank-balanced for the b128 fragment reads).
    __shared__ __align__(16) _Float16 Bs[64][136];

    const int t    = threadIdx.x;
    const int wave = t >> 6;
    const int lane = t & 63;
    const int lrow = lane & 15;   // A row-in-tile / B+D column (code slot)
    const int quad = lane >> 4;

    const int R0 = blockIdx.x * 256 + wave * 64;   // this wave's first row

    // ---- Load A fragments (hi/lo split) straight from global into regs.
    // MFMA A layout: lane holds A[m=lane&15][k=quad*8+j], j=0..7.
    f16x8 Ah[4][2], Al[4][2];
#pragma unroll
    for (int mt = 0; mt < 4; ++mt) {
        const float* xr = X + (size_t)(R0 + mt * 16 + lrow) * D;
#pragma unroll
        for (int ks = 0; ks < 2; ++ks) {
            const int k0 = ks * 32 + quad * 8;
            float4 v0 = *(const float4*)(xr + k0);
            float4 v1 = *(const float4*)(xr + k0 + 4);
            float xs[8] = {v0.x, v0.y, v0.z, v0.w, v1.x, v1.y, v1.z, v1.w};
            f16x8 h, l;
#pragma unroll
            for (int j = 0; j < 8; ++j) {
                _Float16 hj = (_Float16)xs[j];
                h[j] = hj;
                l[j] = (_Float16)(xs[j] - (float)hj);
            }
            Ah[mt][ks] = h;
            Al[mt][ks] = l;
        }
    }

    float bestd[4][4];
    int   besti[4][4];
#pragma unroll
    for (int mt = 0; mt < 4; ++mt)
#pragma unroll
        for (int r = 0; r < 4; ++r) { bestd[mt][r] = 3.0e38f; besti[mt][r] = 0; }

    for (int chunk = 0; chunk < K_CODES / 64; ++chunk) {
        __syncthreads();   // previous chunk's readers done
        // ---- Stage 64 codes: convert fp32 -> f16 hi|lo into LDS.
#pragma unroll
        for (int i = 0; i < 4; ++i) {
            int q    = i * 256 + t;       // float4 id 0..1023 (coalesced)
            int code = q >> 4;
            int kq   = (q & 15) * 4;
            float4 v = *(const float4*)(CB + (size_t)(chunk * 64 + code) * D + kq);
            f16x4 h, l;
            h[0] = (_Float16)v.x; l[0] = (_Float16)(v.x - (float)h[0]);
            h[1] = (_Float16)v.y; l[1] = (_Float16)(v.y - (float)h[1]);
            h[2] = (_Float16)v.z; l[2] = (_Float16)(v.z - (float)h[2]);
            h[3] = (_Float16)v.w; l[3] = (_Float16)(v.w - (float)h[3]);
            *(f16x4*)&Bs[code][kq]      = h;
            *(f16x4*)&Bs[code][64 + kq] = l;
        }
        __syncthreads();

#pragma unroll
        for (int ct = 0; ct < 4; ++ct) {
            // B layout: lane holds B[k=quad*8+j][n=lane&15] = CB'[code][k..]
            const _Float16* bp = &Bs[ct * 16 + lrow][quad * 8];
            f16x8 Bh0 = *(const f16x8*)(bp);
            f16x8 Bh1 = *(const f16x8*)(bp + 32);
            f16x8 Bl0 = *(const f16x8*)(bp + 64);
            f16x8 Bl1 = *(const f16x8*)(bp + 96);
            const int   c  = chunk * 64 + ct * 16 + lrow;
            const float cs = csqr[c];
#pragma unroll
            for (int mt = 0; mt < 4; ++mt) {
                f32x4 acc = {0.f, 0.f, 0.f, 0.f};
                acc = __builtin_amdgcn_mfma_f32_16x16x32_f16(Ah[mt][0], Bh0, acc, 0, 0, 0);
                acc = __builtin_amdgcn_mfma_f32_16x16x32_f16(Ah[mt][1], Bh1, acc, 0, 0, 0);
                acc = __builtin_amdgcn_mfma_f32_16x16x32_f16(Al[mt][0], Bh0, acc, 0, 0, 0);
                acc = __builtin_amdgcn_mfma_f32_16x16x32_f16(Al[mt][1], Bh1, acc, 0, 0, 0);
                acc = __builtin_amdgcn_mfma_f32_16x16x32_f16(Ah[mt][0], Bl0, acc, 0, 0, 0);
                acc = __builtin_amdgcn_mfma_f32_16x16x32_f16(Ah[mt][1], Bl1, acc, 0, 0, 0);
                acc = __builtin_amdgcn_mfma_f32_16x16x32_f16(Al[mt][0], Bl0, acc, 0, 0, 0);
                acc = __builtin_amdgcn_mfma_f32_16x16x32_f16(Al[mt][1], Bl1, acc, 0, 0, 0);
                // D layout: lane holds D[row=quad*4+r][col=lane&15].
                // Codes ascend monotonically across (chunk, ct) for fixed
                // lane -> strict < keeps the first minimum (np.argmin).
#pragma unroll
                for (int r = 0; r < 4; ++r) {
                    float s = fmaf(-2.0f, acc[r], cs);
                    if (s < bestd[mt][r]) { bestd[mt][r] = s; besti[mt][r] = c; }
                }
            }
        }
    }

    // ---- Reduce across the 16 code-columns (low 4 lane bits), lexicographic
    // (dist, idx) to keep np.argmin first-min semantics on exact ties.
#pragma unroll
    for (int mt = 0; mt < 4; ++mt)
#pragma unroll
        for (int r = 0; r < 4; ++r) {
            float d = bestd[mt][r];
            int   i = besti[mt][r];
#pragma unroll
            for (int m = 1; m < 16; m <<= 1) {
                float od = __shfl_xor(d, m, 64);
                int   oi = __shfl_xor(i, m, 64);
                if (od < d || (od == d && oi < i)) { d = od; i = oi; }
            }
            if (lrow == 0) {
                int row = R0 + mt * 16 + quad * 4 + r;
                idx_out[row]  = i;
                idxf_out[row] = (float)i;
            }
        }
}

// ---------------------------------------------------------------------------
// K2: gather z_q = codebook[idx], accumulate loss = 1.25*mean((x-q)^2)
// ---------------------------------------------------------------------------
__global__ __launch_bounds__(256)
void gather_kernel(const float* __restrict__ X, const float* __restrict__ CB,
                   const int* __restrict__ idx,
                   float* __restrict__ zq, float* __restrict__ loss) {
    const int tid    = blockIdx.x * 256 + threadIdx.x;
    const int nquads = N_ROWS * (D / 4);       // float4 units
    const int stride = gridDim.x * 256;
    float acc = 0.0f;
    for (int q = tid; q < nquads; q += stride) {
        int row = q >> 4;          // 16 float4 per row
        int d4  = q & 15;
        int k   = idx[row];
        float4 x = ((const float4*)X)[q];
        float4 c = ((const float4*)(CB + (size_t)k * D))[d4];
        ((float4*)zq)[q] = c;      // z_q forward value == quantize
        float dx = x.x - c.x, dy = x.y - c.y, dz = x.z - c.z, dw = x.w - c.w;
        acc += dx * dx + dy * dy + dz * dz + dw * dw;
    }
    __shared__ float red[256];
    red[threadIdx.x] = acc;
    __syncthreads();
    for (int s = 128; s > 0; s >>= 1) {
        if (threadIdx.x < s) red[threadIdx.x] += red[threadIdx.x + s];
        __syncthreads();
    }
    if (threadIdx.x == 0)
        atomicAdd(loss, red[0] * (1.25f / (float)(N_ROWS * D)));
}

// ---------------------------------------------------------------------------
extern "C" void kernel_launch(void* const* d_in, const int* in_sizes, int n_in,
                              void* d_out, int out_size, void* d_ws,
                              size_t ws_size, hipStream_t stream) {
    const float* X  = (const float*)d_in[0];   // inputs  [131072,64]
    const float* CB = (const float*)d_in[1];   // codebook [1024,64]

    float* out  = (float*)d_out;
    float* loss = out;                                   // [0]
    float* zq   = out + 1;                               // [1 .. 8388608]
    float* idxf = out + 1 + (size_t)N_ROWS * D;          // indices as float

    float* csqr = (float*)d_ws;                          // 1024 floats
    int*   idx  = (int*)((char*)d_ws + 4096);            // 131072 ints

    hipLaunchKernelGGL(csqr_kernel, dim3(4), dim3(256), 0, stream,
                       CB, csqr, loss);
    hipLaunchKernelGGL(argmin_kernel, dim3(N_ROWS / 256), dim3(256), 0, stream,
                       X, CB, csqr, idx, idxf);
    hipLaunchKernelGGL(gather_kernel, dim3(2048), dim3(256), 0, stream,
                       X, CB, idx, zq, loss);
}